// Round 8
// baseline (132.702 us; speedup 1.0000x reference)
//
#include <hip/hip_runtime.h>
#include <math.h>

// Hit-miss transform: out[i][j] = min_{di,dj}(x[i+di][j+dj] - Khit[di][dj])
//                               - max_{di,dj}(x[i+di][j+dj] - Kmiss[di][dj])
// H=W=4096 fp32 input, 5x5 kernels, output 4092x4092 fp32.
//
// R11: turn OFF the max-occupancy register squeeze with the correct knob.
// History: all compiler-liked variants pin at 32-52 VGPR with ~142 VALU
// instr/px vs 75 core (remat + v_mov storm); R10 proved __launch_bounds__'
// 2nd arg is only a cap-floor (VGPR stayed 32, codegen got worse). The
// attribute amdgpu_waves_per_eu(4,4) sets MAX waves/EU=4: allocator budget
// becomes 128 VGPR and the occupancy-squeeze heuristic deactivates, letting
// R5's streaming engine (rows loaded once, accumulators resident) actually
// live in registers. Grid 4092 = 4x1023 -> 4 blocks/CU = 1024 resident =
// 4 rounds at >=99.6% fill. Decisive test: VGPR must leave the 32-40 band;
// if not, remat is not pressure-driven -> revert R4, declare ceiling.
// Engine is R5 verbatim (bit-exact, same IEEE ops -> absmax 0.0).

constexpr int KS  = 5;
constexpr int WW  = 4096;
constexpr int HO  = 4092;
constexpr int WO  = 4092;
constexpr int CG  = WO / 4;   // 1023 column groups
constexpr int RPT = 4;        // output rows per thread (4092 = 4*1023)

__device__ __forceinline__ float min3f(float a, float b, float c) {
    float d;
    asm("v_min3_f32 %0, %1, %2, %3" : "=v"(d) : "v"(a), "v"(b), "v"(c));
    return d;
}
__device__ __forceinline__ float max3f(float a, float b, float c) {
    float d;
    asm("v_max3_f32 %0, %1, %2, %3" : "=v"(d) : "v"(a), "v"(b), "v"(c));
    return d;
}

__device__ __forceinline__ float red5_min(float t0, float t1, float t2, float t3, float t4) {
    return min3f(min3f(t0, t1, t2), t3, t4);
}
__device__ __forceinline__ float red5_max(float t0, float t1, float t2, float t3, float t4) {
    return max3f(max3f(t0, t1, t2), t3, t4);
}
__device__ __forceinline__ float red5acc_min(float acc, float t0, float t1, float t2, float t3, float t4) {
    return fminf(min3f(t0, t1, t2), min3f(t3, t4, acc));
}
__device__ __forceinline__ float red5acc_max(float acc, float t0, float t1, float t2, float t3, float t4) {
    return fmaxf(max3f(t0, t1, t2), max3f(t3, t4, acc));
}

__attribute__((amdgpu_waves_per_eu(4, 4)))
__global__ __launch_bounds__(256) void hitmiss_kernel(
    const float* __restrict__ x,
    const float* __restrict__ kh,
    const float* __restrict__ km,
    float* __restrict__ out)
{
    const int cg = blockIdx.x * blockDim.x + threadIdx.x;  // column group
    if (cg >= CG) return;
    const int j0 = cg * 4;
    const int r0 = blockIdx.y * RPT;

    // Kernel weights: uniform addresses -> scalar (SGPR) loads.
    float wh[KS * KS], wm[KS * KS];
#pragma unroll
    for (int k = 0; k < KS * KS; ++k) {
        wh[k] = kh[k];
        wm[k] = km[k];
    }

    const float* base = x + (size_t)r0 * WW + j0;

    // Accumulators for RPT output rows x 4 pixels — with the 128-VGPR budget
    // these stay register-resident alongside the row values.
    float mn[RPT][4], mx[RPT][4];

#pragma unroll
    for (int i = 0; i < RPT + 4; ++i) {
        // Load input row r0+i exactly once (2x dwordx4), consume, discard.
        float4 a = *reinterpret_cast<const float4*>(base + (size_t)i * WW);
        float4 b = *reinterpret_cast<const float4*>(base + (size_t)i * WW + 4);
        const float v[8] = {a.x, a.y, a.z, a.w, b.x, b.y, b.z, b.w};

#pragma unroll
        for (int o = 0; o < RPT; ++o) {
            const int di = i - o;              // static after unroll
            if (di < 0 || di > KS - 1) continue;
            const int kb = di * KS;
            const float h0 = wh[kb + 0], h1 = wh[kb + 1], h2 = wh[kb + 2],
                        h3 = wh[kb + 3], h4 = wh[kb + 4];
            const float m0 = wm[kb + 0], m1 = wm[kb + 1], m2 = wm[kb + 2],
                        m3 = wm[kb + 3], m4 = wm[kb + 4];

#pragma unroll
            for (int p = 0; p < 4; ++p) {
                const float t0 = v[p + 0] - h0;
                const float t1 = v[p + 1] - h1;
                const float t2 = v[p + 2] - h2;
                const float t3 = v[p + 3] - h3;
                const float t4 = v[p + 4] - h4;
                const float u0 = v[p + 0] - m0;
                const float u1 = v[p + 1] - m1;
                const float u2 = v[p + 2] - m2;
                const float u3 = v[p + 3] - m3;
                const float u4 = v[p + 4] - m4;
                if (di == 0) {
                    mn[o][p] = red5_min(t0, t1, t2, t3, t4);
                    mx[o][p] = red5_max(u0, u1, u2, u3, u4);
                } else {
                    mn[o][p] = red5acc_min(mn[o][p], t0, t1, t2, t3, t4);
                    mx[o][p] = red5acc_max(mx[o][p], u0, u1, u2, u3, u4);
                }
            }
        }

        // Output row o = i-4 complete; store and free its accumulators.
        if (i >= KS - 1) {
            const int o = i - (KS - 1);
            float4 oo;
            oo.x = mn[o][0] - mx[o][0];
            oo.y = mn[o][1] - mx[o][1];
            oo.z = mn[o][2] - mx[o][2];
            oo.w = mn[o][3] - mx[o][3];
            *reinterpret_cast<float4*>(out + (size_t)(r0 + o) * WO + j0) = oo;
        }
    }
}

extern "C" void kernel_launch(void* const* d_in, const int* in_sizes, int n_in,
                              void* d_out, int out_size, void* d_ws, size_t ws_size,
                              hipStream_t stream) {
    const float* x  = (const float*)d_in[0];
    const float* kh = (const float*)d_in[1];
    const float* km = (const float*)d_in[2];
    float* out = (float*)d_out;

    dim3 block(256, 1, 1);
    dim3 grid((CG + 255) / 256, HO / RPT, 1);  // 4 x 1023 = 4092 blocks
    hipLaunchKernelGGL(hitmiss_kernel, grid, block, 0, stream, x, kh, km, out);
}